// Round 6
// baseline (449.982 us; speedup 1.0000x reference)
//
#include <hip/hip_runtime.h>
#include <stdint.h>
#include <math.h>

// MultiGeometryAttention — f32 in/out. B=2 T=2048 C=1024 H=16 HD=64.
// heads 0-5 sdpa(0.125) | 6-9 hyperbolic(curvature) | 10-15 cos-normalized sdpa(8).
// Split-bf16 (no fp32 MFMA on CDNA4): x*W via A'=[hi|lo|hi],B'=[hi|hi|lo] K'=3K GEMM;
// attention scores via 3-product split (qh*kh + ql*kh + qh*kl) MFMA.
// R6: BARRIER-FREE attention. MFMA B-frags for QK^T and PV are 8 contiguous bf16 at a
// lane-indexed row of Ks/Vt -> load fragments DIRECTLY from global (L2-hit), no K/V LDS,
// no __syncthreads at all. 1 wave per block (32 q-rows), 2048 blocks, wave-private P
// tile (4KB LDS). Static-max softmax (R5). tq/tk = sqrt(1/c+|.|^2) precomputed in prep.
// WS offsets (bytes), peak 94,896,128 (proven):
//   A'x [0,25165824) | B'w [25165824,44040192) | qkvf f32 [44040192,94371840)
//   post-gemm1: Qs [0,16777216) Ks [16777216,33554432) Vt [33554432,41943040)
//   A'y [44040192,69206016) | B'pw [69206016,75497472) | qq/kk [94371840,94896128)

typedef __bf16 bf16x8 __attribute__((ext_vector_type(8)));
typedef float f32x4 __attribute__((ext_vector_type(4)));

static __device__ __forceinline__ float bf2f(unsigned short u) {
  union { unsigned int i; float f; } v; v.i = ((unsigned int)u) << 16; return v.f;
}
static __device__ __forceinline__ unsigned short f2bf(float f) {
  union { float f; unsigned int i; } v; v.f = f;
  unsigned int x = v.i;
  x += 0x7fffu + ((x >> 16) & 1u);   // RNE
  return (unsigned short)(x >> 16);
}

// direct global->LDS async copy, 16B/lane (gemm staging only).
static __device__ __forceinline__ void async_copy16(const void* gsrc, void* ldst) {
  auto* lp = reinterpret_cast<__attribute__((address_space(3))) unsigned int*>(
      reinterpret_cast<uintptr_t>(ldst));
  auto* gp = reinterpret_cast<const __attribute__((address_space(1))) unsigned int*>(
      reinterpret_cast<uintptr_t>(gsrc));
  __builtin_amdgcn_global_load_lds(gp, lp, 16, 0, 0);
}

// f32 [rows][1024] -> split bf16 [rows][3072]. PAT=0 (A): [hi|lo|hi]; PAT=1 (B): [hi|hi|lo].
template <int PAT>
__global__ __launch_bounds__(256) void split3(const float* __restrict__ in,
                                              unsigned short* __restrict__ out) {
  const int row = blockIdx.x;
  const int kq = threadIdx.x * 4;
  const f32x4 x = *(const f32x4*)(in + (size_t)row * 1024 + kq);
  unsigned short hi[4], lo[4];
#pragma unroll
  for (int i = 0; i < 4; ++i) {
    hi[i] = f2bf(x[i]);
    lo[i] = f2bf(x[i] - bf2f(hi[i]));   // exact residual in f32
  }
  uint2 uh, ul;
  uh.x = (unsigned)hi[0] | ((unsigned)hi[1] << 16);
  uh.y = (unsigned)hi[2] | ((unsigned)hi[3] << 16);
  ul.x = (unsigned)lo[0] | ((unsigned)lo[1] << 16);
  ul.y = (unsigned)lo[2] | ((unsigned)lo[3] << 16);
  unsigned short* op = out + (size_t)row * 3072 + kq;
  *(uint2*)(op)        = uh;
  *(uint2*)(op + 1024) = PAT ? uh : ul;
  *(uint2*)(op + 2048) = PAT ? ul : uh;
}

// C[m][n] = sum_k A[m][k]*B[n][k] (+bias[n]) -> f32. 128x128 tile, BK=64, 4 waves,
// 16x16x32 bf16 MFMA, XOR-swizzled LDS (verified).
template <int HASBIAS>
__global__ __launch_bounds__(256) void gemm_bt(
    const unsigned short* __restrict__ A, const unsigned short* __restrict__ Bm,
    float* __restrict__ C, const float* __restrict__ bias, int N_, int K_) {
  alignas(16) __shared__ unsigned short smA[128 * 64];
  alignas(16) __shared__ unsigned short smB[128 * 64];
  const int tid = threadIdx.x;
  const int lane = tid & 63;
  const int wv = tid >> 6;
  const int wm = wv >> 1, wn = wv & 1;
  const long m0 = (long)blockIdx.y * 128, n0 = (long)blockIdx.x * 128;

  const f32x4 zero4 = {0.f, 0.f, 0.f, 0.f};
  f32x4 acc[4][4];
#pragma unroll
  for (int i = 0; i < 4; ++i)
#pragma unroll
    for (int j = 0; j < 4; ++j) acc[i][j] = zero4;

  int mrow[4], gg[4];
#pragma unroll
  for (int w = 0; w < 4; ++w) {
    int c = w * 256 + tid;
    mrow[w] = c >> 3;
    gg[w] = (c & 7) ^ ((c >> 3) & 7);
  }

  const int kTiles = K_ >> 6;
  for (int kt = 0; kt < kTiles; ++kt) {
    if (kt) __syncthreads();
    const int kb = kt << 6;
#pragma unroll
    for (int w = 0; w < 4; ++w) {
      const int c = w * 256 + tid;
      async_copy16(A + (size_t)(m0 + mrow[w]) * K_ + kb + gg[w] * 8,
                   (char*)smA + c * 16);
      async_copy16(Bm + (size_t)(n0 + mrow[w]) * K_ + kb + gg[w] * 8,
                   (char*)smB + c * 16);
    }
    __syncthreads();
#pragma unroll
    for (int ks = 0; ks < 2; ++ks) {
      bf16x8 af[4], bg[4];
#pragma unroll
      for (int i = 0; i < 4; ++i) {
        const int ra = wm * 64 + i * 16 + (lane & 15);
        const int ga = (ks * 4 + (lane >> 4)) ^ (ra & 7);
        af[i] = *(const bf16x8*)((const char*)smA + ra * 128 + ga * 16);
        const int rb = wn * 64 + i * 16 + (lane & 15);
        const int gb2 = (ks * 4 + (lane >> 4)) ^ (rb & 7);
        bg[i] = *(const bf16x8*)((const char*)smB + rb * 128 + gb2 * 16);
      }
#pragma unroll
      for (int i = 0; i < 4; ++i)
#pragma unroll
        for (int j = 0; j < 4; ++j)
          acc[i][j] = __builtin_amdgcn_mfma_f32_16x16x32_bf16(af[i], bg[j], acc[i][j], 0, 0, 0);
    }
  }

  const int r0 = wm * 64 + (lane >> 4) * 4;
  const int c0 = wn * 64 + (lane & 15);
#pragma unroll
  for (int j = 0; j < 4; ++j) {
    const long col = n0 + c0 + j * 16;
    float bv = 0.f;
    if (HASBIAS) bv = bias[col];
#pragma unroll
    for (int i = 0; i < 4; ++i) {
#pragma unroll
      for (int r = 0; r < 4; ++r) {
        const long row = m0 + r0 + i * 16 + r;
        C[row * N_ + col] = acc[i][j][r] + bv;
      }
    }
  }
}

// prep: per (b,h,ttile of 64): rotary q,k (f32); |q|^2,|k|^2; normalize h>=10;
// split q,k -> Qs/Ks [b][h][t][hi(64)|lo(64)] bf16; transpose v -> Vt[b][h][d][2048] bf16.
// For hyperbolic heads (6..9) store tq=sqrt(1/c+|q|^2), tk=sqrt(1/c+|k|^2) in qq/kk.
__global__ __launch_bounds__(256) void prep(
    const float* __restrict__ qkvf, unsigned short* __restrict__ Qs,
    unsigned short* __restrict__ Ks, unsigned short* __restrict__ Vt,
    float* __restrict__ qq, float* __restrict__ kk, const float* __restrict__ curvg) {
  __shared__ unsigned short Vl[64 * 66];
  const int tid = threadIdx.x;
  const int zz = blockIdx.x;
  const int ttile = zz & 31, bh = zz >> 5;
  const int b = bh >> 4, h = bh & 15;
  const int t0 = ttile * 64;
  const int tr = tid >> 2, seg = tid & 3;
  const int t = t0 + tr;
  const float* src = qkvf + ((size_t)(b * 2048 + t)) * 3072 + h * 64 + seg * 16;

  float qv[16], kv[16], vv[16];
#pragma unroll
  for (int c = 0; c < 4; ++c) {
    const f32x4 a  = *(const f32x4*)(src + c * 4);
    const f32x4 bb = *(const f32x4*)(src + 1024 + c * 4);
    const f32x4 cc = *(const f32x4*)(src + 2048 + c * 4);
#pragma unroll
    for (int e = 0; e < 4; ++e) { qv[c*4+e] = a[e]; kv[c*4+e] = bb[e]; vv[c*4+e] = cc[e]; }
  }
  float qr[16], kr[16];
#pragma unroll
  for (int e = 0; e < 16; ++e) {
    const int d = seg * 16 + e;
    const int i = d & 31;
    const float invf = exp2f(-0.41524101186109286f * (float)i);  // 10000^(-i/32)
    float sn, cs;
    sincosf((float)t * invf, &sn, &cs);
    const float qo = __shfl_xor(qv[e], 2, 64);
    const float ko = __shfl_xor(kv[e], 2, 64);
    qr[e] = (d < 32) ? (qv[e] * cs + qo * sn) : (qv[e] * cs - qo * sn);
    kr[e] = (d < 32) ? (kv[e] * cs + ko * sn) : (kv[e] * cs - ko * sn);
  }
  float sq = 0.f, sk = 0.f;
#pragma unroll
  for (int e = 0; e < 16; ++e) { sq += qr[e] * qr[e]; sk += kr[e] * kr[e]; }
  sq += __shfl_xor(sq, 1, 64); sq += __shfl_xor(sq, 2, 64);
  sk += __shfl_xor(sk, 1, 64); sk += __shfl_xor(sk, 2, 64);
  if (h >= 10) {
    const float rq = 1.0f / fmaxf(sqrtf(sq), 1e-12f);
    const float rk = 1.0f / fmaxf(sqrtf(sk), 1e-12f);
#pragma unroll
    for (int e = 0; e < 16; ++e) { qr[e] *= rq; kr[e] *= rk; }
  }
  if (seg == 0) {
    const int idx = b * 32768 + h * 2048 + t;
    float oq = sq, ok = sk;
    if (h >= 6 && h < 10) {
      const float invc = 1.0f / curvg[h - 6];
      oq = sqrtf(invc + sq);
      ok = sqrtf(invc + sk);
    }
    qq[idx] = oq;
    kk[idx] = ok;
  }
  {
    unsigned int wh[8], wl[8];
#pragma unroll
    for (int p = 0; p < 8; ++p) {
      unsigned short h0 = f2bf(qr[2*p]), h1 = f2bf(qr[2*p+1]);
      unsigned short l0 = f2bf(qr[2*p] - bf2f(h0)), l1 = f2bf(qr[2*p+1] - bf2f(h1));
      wh[p] = (unsigned)h0 | ((unsigned)h1 << 16);
      wl[p] = (unsigned)l0 | ((unsigned)l1 << 16);
    }
    unsigned short* qdst = Qs + ((size_t)bh * 2048 + t) * 128 + seg * 16;
    *(uint4*)(qdst)      = uint4{wh[0], wh[1], wh[2], wh[3]};
    *(uint4*)(qdst + 8)  = uint4{wh[4], wh[5], wh[6], wh[7]};
    *(uint4*)(qdst + 64) = uint4{wl[0], wl[1], wl[2], wl[3]};
    *(uint4*)(qdst + 72) = uint4{wl[4], wl[5], wl[6], wl[7]};
#pragma unroll
    for (int p = 0; p < 8; ++p) {
      unsigned short h0 = f2bf(kr[2*p]), h1 = f2bf(kr[2*p+1]);
      unsigned short l0 = f2bf(kr[2*p] - bf2f(h0)), l1 = f2bf(kr[2*p+1] - bf2f(h1));
      wh[p] = (unsigned)h0 | ((unsigned)h1 << 16);
      wl[p] = (unsigned)l0 | ((unsigned)l1 << 16);
    }
    unsigned short* kdst = Ks + ((size_t)bh * 2048 + t) * 128 + seg * 16;
    *(uint4*)(kdst)      = uint4{wh[0], wh[1], wh[2], wh[3]};
    *(uint4*)(kdst + 8)  = uint4{wh[4], wh[5], wh[6], wh[7]};
    *(uint4*)(kdst + 64) = uint4{wl[0], wl[1], wl[2], wl[3]};
    *(uint4*)(kdst + 72) = uint4{wl[4], wl[5], wl[6], wl[7]};
  }
#pragma unroll
  for (int e = 0; e < 16; ++e) Vl[(seg * 16 + e) * 66 + tr] = f2bf(vv[e]);
  __syncthreads();
  {
    const int d = tid >> 2, tch = (tid & 3) * 16;
    unsigned int wv2[8];
#pragma unroll
    for (int p = 0; p < 8; ++p) {
      const unsigned short a0 = Vl[d * 66 + tch + 2*p];
      const unsigned short a1 = Vl[d * 66 + tch + 2*p + 1];
      wv2[p] = (unsigned)a0 | ((unsigned)a1 << 16);
    }
    unsigned short* vdst = Vt + ((size_t)bh * 64 + d) * 2048 + t0 + tch;
    *(uint4*)(vdst)     = uint4{wv2[0], wv2[1], wv2[2], wv2[3]};
    *(uint4*)(vdst + 8) = uint4{wv2[4], wv2[5], wv2[6], wv2[7]};
  }
}

// Barrier-free MFMA flash attention. 1 wave per block, 32 q-rows (qw = 63-(z>>5),
// biggest causal tiles first). All K/V fragments loaded directly from global
// (8 contiguous bf16 at a lane-indexed row = natural MFMA B-frag). Wave-private
// bf16 P tile in LDS (C->A layout round-trip, XOR-swizzled). Static-max softmax;
// l via ones-MFMA on the same bf16 P (rounding cancels in o/l).
__global__ __launch_bounds__(64) void attn_mfma(
    const unsigned short* __restrict__ Qs, const unsigned short* __restrict__ Ks,
    const unsigned short* __restrict__ Vt, const float* __restrict__ tqq,
    const float* __restrict__ tkk, const float* __restrict__ curvg,
    unsigned short* __restrict__ Ay) {
  alignas(16) __shared__ unsigned short Pl[32 * 64];   // 4KB, wave-private
  const int lane = threadIdx.x;
  const int quad = lane >> 4, c15 = lane & 15;
  const int z = blockIdx.x, bh = z & 31, qw = 63 - (z >> 5);
  const int b = bh >> 4, h = bh & 15;
  const int geom = (h < 6) ? 0 : ((h < 10) ? 1 : 2);
  const int qrow0 = qw * 32;
  const f32x4 zero4 = {0.f, 0.f, 0.f, 0.f};

  // Q fragments (A-layout: m=c15, k=quad*8+j), hi & lo, 2 q-subtiles x 2 k-steps
  bf16x8 qh[2][2], ql[2][2];
#pragma unroll
  for (int qi = 0; qi < 2; ++qi)
#pragma unroll
    for (int st = 0; st < 2; ++st) {
      const size_t qa =
          ((size_t)bh * 2048 + qrow0 + qi * 16 + c15) * 128 + st * 32 + quad * 8;
      qh[qi][st] = *(const bf16x8*)(Qs + qa);
      ql[qi][st] = *(const bf16x8*)(Qs + qa + 64);
    }

  float curv = 1.f, sic = 1.f, sscale = 0.125f, Moff = 16.0f;
  f32x4 tq4[2] = {zero4, zero4};
  if (geom == 1) {
    curv = curvg[h - 6];
    sic = sqrtf(1.0f / curv);
    Moff = 4.0f;
#pragma unroll
    for (int qi = 0; qi < 2; ++qi)
      tq4[qi] = *(const f32x4*)(tqq + bh * 2048 + qrow0 + qi * 16 + quad * 4);
  } else if (geom == 2) {
    sscale = 8.0f;
    Moff = 8.0f;
  }

  const __bf16 one_b = (__bf16)1.0f;
  const bf16x8 ones = {one_b, one_b, one_b, one_b, one_b, one_b, one_b, one_b};

  f32x4 o[2][4];
  f32x4 ol[2] = {zero4, zero4};
#pragma unroll
  for (int qi = 0; qi < 2; ++qi)
#pragma unroll
    for (int dj = 0; dj < 4; ++dj) o[qi][dj] = zero4;

  const int nkt = (qw >> 1) + 1;
  for (int kt = 0; kt < nkt; ++kt) {
    const int kb = kt * 64;

    // ---- S = Q.K'^T : 3-product split, K frags straight from global
    f32x4 s[2][4];
#pragma unroll
    for (int qi = 0; qi < 2; ++qi)
#pragma unroll
      for (int kj = 0; kj < 4; ++kj) s[qi][kj] = zero4;
#pragma unroll
    for (int st = 0; st < 2; ++st) {
#pragma unroll
      for (int kj = 0; kj < 4; ++kj) {
        const unsigned short* kr =
            Ks + ((size_t)bh * 2048 + kb + kj * 16 + c15) * 128 + st * 32 + quad * 8;
        const bf16x8 bhf = *(const bf16x8*)(kr);
        const bf16x8 blf = *(const bf16x8*)(kr + 64);
#pragma unroll
        for (int qi = 0; qi < 2; ++qi) {
          s[qi][kj] = __builtin_amdgcn_mfma_f32_16x16x32_bf16(qh[qi][st], bhf, s[qi][kj], 0, 0, 0);
          s[qi][kj] = __builtin_amdgcn_mfma_f32_16x16x32_bf16(ql[qi][st], bhf, s[qi][kj], 0, 0, 0);
          s[qi][kj] = __builtin_amdgcn_mfma_f32_16x16x32_bf16(qh[qi][st], blf, s[qi][kj], 0, 0, 0);
        }
      }
    }

    // ---- p = exp(score - M_static); causal mask -> 0 (only last ktile straddles);
    //      write bf16 P (truncate) into wave-private swizzled LDS
    const bool needmask = (kt == nkt - 1);
#pragma unroll
    for (int qi = 0; qi < 2; ++qi) {
      const int qbase = qrow0 + qi * 16 + quad * 4;   // + r
#pragma unroll
      for (int kj = 0; kj < 4; ++kj) {
        const int skey = kj * 16 + c15;
        const int key = kb + skey;
        const f32x4 d4 = s[qi][kj];
        f32x4 p;
        if (geom == 1) {
          const float tk = tkk[bh * 2048 + key];
#pragma unroll
          for (int r = 0; r < 4; ++r) {
            const float a = fmaxf(curv * (tq4[qi][r] * tk - d4[r]), 1.0f + 1e-7f);
            const float dis = sic * __logf(a + sqrtf(a * a - 1.0f));
            p[r] = __expf(__builtin_amdgcn_rcpf(1e-6f + dis) - Moff);
          }
        } else {
#pragma unroll
          for (int r = 0; r < 4; ++r) p[r] = __expf(d4[r] * sscale - Moff);
        }
        if (needmask) {
#pragma unroll
          for (int r = 0; r < 4; ++r)
            if (key > qbase + r) p[r] = 0.0f;
        }
#pragma unroll
        for (int r = 0; r < 4; ++r) {
          union { float f; unsigned u; } pv; pv.f = p[r];
          const int row = qi * 16 + quad * 4 + r;
          const int g = (skey >> 3) ^ (row & 7);
          Pl[row * 64 + g * 8 + (skey & 7)] = (unsigned short)(pv.u >> 16);
        }
      }
    }

    // ---- PV: O += P.V^T ; l += P.1 — V frags straight from global (same wave,
    //      compiler orders ds_write -> lgkmcnt -> ds_read)
#pragma unroll
    for (int ks2 = 0; ks2 < 2; ++ks2) {
      bf16x8 av[2];
#pragma unroll
      for (int qi = 0; qi < 2; ++qi) {
        const int m = qi * 16 + c15;
        const int g = (ks2 * 4 + quad) ^ (m & 7);
        av[qi] = *(const bf16x8*)(Pl + m * 64 + g * 8);
        ol[qi] = __builtin_amdgcn_mfma_f32_16x16x32_bf16(av[qi], ones, ol[qi], 0, 0, 0);
      }
#pragma unroll
      for (int dj = 0; dj < 4; ++dj) {
        const bf16x8 bv = *(const bf16x8*)(
            Vt + ((size_t)bh * 64 + dj * 16 + c15) * 2048 + kb + ks2 * 32 + quad * 8);
#pragma unroll
        for (int qi = 0; qi < 2; ++qi)
          o[qi][dj] = __builtin_amdgcn_mfma_f32_16x16x32_bf16(av[qi], bv, o[qi][dj], 0, 0, 0);
      }
    }
  }

  // ---- epilogue: O/l -> A'y split [hi|lo|hi]
#pragma unroll
  for (int qi = 0; qi < 2; ++qi) {
    f32x4 invl;
#pragma unroll
    for (int r = 0; r < 4; ++r) invl[r] = __builtin_amdgcn_rcpf(ol[qi][r]);
#pragma unroll
    for (int dj = 0; dj < 4; ++dj) {
      const int d = dj * 16 + c15;
#pragma unroll
      for (int r = 0; r < 4; ++r) {
        const float val = o[qi][dj][r] * invl[r];
        const int t = qrow0 + qi * 16 + quad * 4 + r;
        const unsigned short hi = f2bf(val);
        const unsigned short lo = f2bf(val - bf2f(hi));
        unsigned short* yp = Ay + ((size_t)(b * 2048 + t)) * 3072 + h * 64 + d;
        yp[0] = hi; yp[1024] = lo; yp[2048] = hi;
      }
    }
  }
}

extern "C" void kernel_launch(void* const* d_in, const int* in_sizes, int n_in,
                              void* d_out, int out_size, void* d_ws, size_t ws_size,
                              hipStream_t stream) {
  const float* x      = (const float*)d_in[0];
  const float* qkv_w  = (const float*)d_in[1];
  const float* proj_w = (const float*)d_in[2];
  const float* proj_b = (const float*)d_in[3];
  const float* curvature = (const float*)d_in[4];
  float* out = (float*)d_out;

  char* ws = (char*)d_ws;
  unsigned short* AX   = (unsigned short*)ws;
  unsigned short* BW   = (unsigned short*)(ws + 25165824);
  float*          QKVF = (float*)(ws + 44040192);
  unsigned short* QS   = (unsigned short*)ws;
  unsigned short* KS   = (unsigned short*)(ws + 16777216);
  unsigned short* VT   = (unsigned short*)(ws + 33554432);
  unsigned short* AY   = (unsigned short*)(ws + 44040192);
  unsigned short* BPW  = (unsigned short*)(ws + 69206016);
  float*          QQ   = (float*)(ws + 94371840);
  float*          KK   = (float*)(ws + 94633984);

  split3<0><<<4096, 256, 0, stream>>>(x, AX);
  split3<1><<<3072, 256, 0, stream>>>(qkv_w, BW);

  gemm_bt<0><<<dim3(24, 32), 256, 0, stream>>>(AX, BW, QKVF, nullptr, 3072, 3072);

  prep<<<1024, 256, 0, stream>>>(QKVF, QS, KS, VT, QQ, KK, curvature);

  split3<1><<<1024, 256, 0, stream>>>(proj_w, BPW);

  attn_mfma<<<2048, 64, 0, stream>>>(QS, KS, VT, QQ, KK, curvature, AY);

  gemm_bt<1><<<dim3(8, 32), 256, 0, stream>>>(AY, BPW, out, proj_b, 1024, 3072);
}

// Round 8
// 389.255 us; speedup vs baseline: 1.1560x; 1.1560x over previous
//
#include <hip/hip_runtime.h>
#include <stdint.h>
#include <math.h>

// MultiGeometryAttention — f32 in/out. B=2 T=2048 C=1024 H=16 HD=64.
// heads 0-5 sdpa(0.125) | 6-9 hyperbolic(curvature) | 10-15 cos-normalized sdpa(8).
// Split-bf16 (no fp32 MFMA): x*W via A'=[hi|lo|hi],B'=[hi|hi|lo] K'=3K GEMM;
// attention scores via 3-product split (qh*kh + ql*kh + qh*kl) MFMA; static-max
// softmax (R5 proof); R7: fragment-linear Q2/K2/V2 tiles (every attn global load is
// lane-linear 16B/lane — no gathers, no K/V LDS, no barriers) + split-K partials
// (chunk=8 ktiles, 5120 single-wave blocks; partial o,l ADD because max is static)
// + attn_reduce (sum chunks, divide, LDS-transpose, write A'y).
// WS (proven peak 94,896,128 B):
//  phase1: A'x [0,25165824) | B'w [25165824,44040192) | QKVF [44040192,94371840)
//  post-prep: Q2 [0,16777216) K2 [16777216,33554432) V2 [33554432,41943040)
//             BPW [44040192,50331648) | PART [50331648,93585408)
//  post-attn: AY [0,25165824) (over Q2/K2) | qq/kk [94371840,94896128)

typedef __bf16 bf16x8 __attribute__((ext_vector_type(8)));
typedef float f32x4 __attribute__((ext_vector_type(4)));

static __device__ __forceinline__ float bf2f(unsigned short u) {
  union { unsigned int i; float f; } v; v.i = ((unsigned int)u) << 16; return v.f;
}
static __device__ __forceinline__ unsigned short f2bf(float f) {
  union { float f; unsigned int i; } v; v.f = f;
  unsigned int x = v.i;
  x += 0x7fffu + ((x >> 16) & 1u);   // RNE
  return (unsigned short)(x >> 16);
}

// direct global->LDS async copy, 16B/lane (gemm staging only).
static __device__ __forceinline__ void async_copy16(const void* gsrc, void* ldst) {
  auto* lp = reinterpret_cast<__attribute__((address_space(3))) unsigned int*>(
      reinterpret_cast<uintptr_t>(ldst));
  auto* gp = reinterpret_cast<const __attribute__((address_space(1))) unsigned int*>(
      reinterpret_cast<uintptr_t>(gsrc));
  __builtin_amdgcn_global_load_lds(gp, lp, 16, 0, 0);
}

// f32 [rows][1024] -> split bf16 [rows][3072]. PAT=0 (A): [hi|lo|hi]; PAT=1 (B): [hi|hi|lo].
template <int PAT>
__global__ __launch_bounds__(256) void split3(const float* __restrict__ in,
                                              unsigned short* __restrict__ out) {
  const int row = blockIdx.x;
  const int kq = threadIdx.x * 4;
  const f32x4 x = *(const f32x4*)(in + (size_t)row * 1024 + kq);
  unsigned short hi[4], lo[4];
#pragma unroll
  for (int i = 0; i < 4; ++i) {
    hi[i] = f2bf(x[i]);
    lo[i] = f2bf(x[i] - bf2f(hi[i]));   // exact residual in f32
  }
  uint2 uh, ul;
  uh.x = (unsigned)hi[0] | ((unsigned)hi[1] << 16);
  uh.y = (unsigned)hi[2] | ((unsigned)hi[3] << 16);
  ul.x = (unsigned)lo[0] | ((unsigned)lo[1] << 16);
  ul.y = (unsigned)lo[2] | ((unsigned)lo[3] << 16);
  unsigned short* op = out + (size_t)row * 3072 + kq;
  *(uint2*)(op)        = uh;
  *(uint2*)(op + 1024) = PAT ? uh : ul;
  *(uint2*)(op + 2048) = PAT ? ul : uh;
}

// C[m][n] = sum_k A[m][k]*B[n][k] (+bias[n]) -> f32. 128x128 tile, BK=64, 4 waves,
// 16x16x32 bf16 MFMA, XOR-swizzled LDS (verified).
template <int HASBIAS>
__global__ __launch_bounds__(256) void gemm_bt(
    const unsigned short* __restrict__ A, const unsigned short* __restrict__ Bm,
    float* __restrict__ C, const float* __restrict__ bias, int N_, int K_) {
  alignas(16) __shared__ unsigned short smA[128 * 64];
  alignas(16) __shared__ unsigned short smB[128 * 64];
  const int tid = threadIdx.x;
  const int lane = tid & 63;
  const int wv = tid >> 6;
  const int wm = wv >> 1, wn = wv & 1;
  const long m0 = (long)blockIdx.y * 128, n0 = (long)blockIdx.x * 128;

  const f32x4 zero4 = {0.f, 0.f, 0.f, 0.f};
  f32x4 acc[4][4];
#pragma unroll
  for (int i = 0; i < 4; ++i)
#pragma unroll
    for (int j = 0; j < 4; ++j) acc[i][j] = zero4;

  int mrow[4], gg[4];
#pragma unroll
  for (int w = 0; w < 4; ++w) {
    int c = w * 256 + tid;
    mrow[w] = c >> 3;
    gg[w] = (c & 7) ^ ((c >> 3) & 7);
  }

  const int kTiles = K_ >> 6;
  for (int kt = 0; kt < kTiles; ++kt) {
    if (kt) __syncthreads();
    const int kb = kt << 6;
#pragma unroll
    for (int w = 0; w < 4; ++w) {
      const int c = w * 256 + tid;
      async_copy16(A + (size_t)(m0 + mrow[w]) * K_ + kb + gg[w] * 8,
                   (char*)smA + c * 16);
      async_copy16(Bm + (size_t)(n0 + mrow[w]) * K_ + kb + gg[w] * 8,
                   (char*)smB + c * 16);
    }
    __syncthreads();
#pragma unroll
    for (int ks = 0; ks < 2; ++ks) {
      bf16x8 af[4], bg[4];
#pragma unroll
      for (int i = 0; i < 4; ++i) {
        const int ra = wm * 64 + i * 16 + (lane & 15);
        const int ga = (ks * 4 + (lane >> 4)) ^ (ra & 7);
        af[i] = *(const bf16x8*)((const char*)smA + ra * 128 + ga * 16);
        const int rb = wn * 64 + i * 16 + (lane & 15);
        const int gb2 = (ks * 4 + (lane >> 4)) ^ (rb & 7);
        bg[i] = *(const bf16x8*)((const char*)smB + rb * 128 + gb2 * 16);
      }
#pragma unroll
      for (int i = 0; i < 4; ++i)
#pragma unroll
        for (int j = 0; j < 4; ++j)
          acc[i][j] = __builtin_amdgcn_mfma_f32_16x16x32_bf16(af[i], bg[j], acc[i][j], 0, 0, 0);
    }
  }

  const int r0 = wm * 64 + (lane >> 4) * 4;
  const int c0 = wn * 64 + (lane & 15);
#pragma unroll
  for (int j = 0; j < 4; ++j) {
    const long col = n0 + c0 + j * 16;
    float bv = 0.f;
    if (HASBIAS) bv = bias[col];
#pragma unroll
    for (int i = 0; i < 4; ++i) {
#pragma unroll
      for (int r = 0; r < 4; ++r) {
        const long row = m0 + r0 + i * 16 + r;
        C[row * N_ + col] = acc[i][j][r] + bv;
      }
    }
  }
}

// prep: rotary q,k; norms; normalize h>=10; tq/tk for hyperbolic; emit FRAGMENT-LINEAR
// tiles: element (frag,quad,c15,j) at frag*512 + quad*128 + c15*8 + j so the attention
// kernel's loads are lane*8-contiguous.
// Q2: per (bh,qw32): frag=(qi*2+st)*2+hl (8 frags, 8KB). K2: per (bh,kt64):
// frag=(st*4+kj)*2+hl (16 frags, 16KB). V2: per (bh,kt64): frag=ks2*4+dj (8 frags, 8KB).
__global__ __launch_bounds__(256) void prep(
    const float* __restrict__ qkvf, unsigned short* __restrict__ Q2,
    unsigned short* __restrict__ K2, unsigned short* __restrict__ V2,
    float* __restrict__ qq, float* __restrict__ kk, const float* __restrict__ curvg) {
  __shared__ unsigned short Vl[64 * 66];
  const int tid = threadIdx.x;
  const int zz = blockIdx.x;
  const int ttile = zz & 31, bh = zz >> 5;
  const int b = bh >> 4, h = bh & 15;
  const int t0 = ttile * 64;
  const int tr = tid >> 2, seg = tid & 3;
  const int t = t0 + tr;
  const float* src = qkvf + ((size_t)(b * 2048 + t)) * 3072 + h * 64 + seg * 16;

  float qv[16], kv[16], vv[16];
#pragma unroll
  for (int c = 0; c < 4; ++c) {
    const f32x4 a  = *(const f32x4*)(src + c * 4);
    const f32x4 bb = *(const f32x4*)(src + 1024 + c * 4);
    const f32x4 cc = *(const f32x4*)(src + 2048 + c * 4);
#pragma unroll
    for (int e = 0; e < 4; ++e) { qv[c*4+e] = a[e]; kv[c*4+e] = bb[e]; vv[c*4+e] = cc[e]; }
  }
  float qr[16], kr[16];
#pragma unroll
  for (int e = 0; e < 16; ++e) {
    const int d = seg * 16 + e;
    const int i = d & 31;
    const float invf = exp2f(-0.41524101186109286f * (float)i);  // 10000^(-i/32)
    float sn, cs;
    sincosf((float)t * invf, &sn, &cs);
    const float qo = __shfl_xor(qv[e], 2, 64);
    const float ko = __shfl_xor(kv[e], 2, 64);
    qr[e] = (d < 32) ? (qv[e] * cs + qo * sn) : (qv[e] * cs - qo * sn);
    kr[e] = (d < 32) ? (kv[e] * cs + ko * sn) : (kv[e] * cs - ko * sn);
  }
  float sq = 0.f, sk = 0.f;
#pragma unroll
  for (int e = 0; e < 16; ++e) { sq += qr[e] * qr[e]; sk += kr[e] * kr[e]; }
  sq += __shfl_xor(sq, 1, 64); sq += __shfl_xor(sq, 2, 64);
  sk += __shfl_xor(sk, 1, 64); sk += __shfl_xor(sk, 2, 64);
  if (h >= 10) {
    const float rq = 1.0f / fmaxf(sqrtf(sq), 1e-12f);
    const float rk = 1.0f / fmaxf(sqrtf(sk), 1e-12f);
#pragma unroll
    for (int e = 0; e < 16; ++e) { qr[e] *= rq; kr[e] *= rk; }
  }
  if (seg == 0) {
    const int idx = b * 32768 + h * 2048 + t;
    float oq = sq, ok = sk;
    if (h >= 6 && h < 10) {
      const float invc = 1.0f / curvg[h - 6];
      oq = sqrtf(invc + sq);
      ok = sqrtf(invc + sk);
    }
    qq[idx] = oq;
    kk[idx] = ok;
  }
  // fragment-linear q/k stores: dims d=seg*16+e -> st=seg>>1, quadA/B, j=e&7
  const int st = seg >> 1;
  const int quadA = (seg * 2) & 3, quadB = (seg * 2 + 1) & 3;
  {
    unsigned int wh[8], wl[8];
#pragma unroll
    for (int p = 0; p < 8; ++p) {
      unsigned short h0 = f2bf(qr[2*p]), h1 = f2bf(qr[2*p+1]);
      unsigned short l0 = f2bf(qr[2*p] - bf2f(h0)), l1 = f2bf(qr[2*p+1] - bf2f(h1));
      wh[p] = (unsigned)h0 | ((unsigned)h1 << 16);
      wl[p] = (unsigned)l0 | ((unsigned)l1 << 16);
    }
    const int qi = (t >> 4) & 1, c15q = t & 15;
    unsigned short* qs = Q2 + ((size_t)bh * 64 + (t >> 5)) * 4096;
    const int fh = ((qi * 2 + st) * 2 + 0) * 512, fl = fh + 512;
    *(uint4*)(qs + fh + quadA * 128 + c15q * 8) = uint4{wh[0], wh[1], wh[2], wh[3]};
    *(uint4*)(qs + fh + quadB * 128 + c15q * 8) = uint4{wh[4], wh[5], wh[6], wh[7]};
    *(uint4*)(qs + fl + quadA * 128 + c15q * 8) = uint4{wl[0], wl[1], wl[2], wl[3]};
    *(uint4*)(qs + fl + quadB * 128 + c15q * 8) = uint4{wl[4], wl[5], wl[6], wl[7]};
#pragma unroll
    for (int p = 0; p < 8; ++p) {
      unsigned short h0 = f2bf(kr[2*p]), h1 = f2bf(kr[2*p+1]);
      unsigned short l0 = f2bf(kr[2*p] - bf2f(h0)), l1 = f2bf(kr[2*p+1] - bf2f(h1));
      wh[p] = (unsigned)h0 | ((unsigned)h1 << 16);
      wl[p] = (unsigned)l0 | ((unsigned)l1 << 16);
    }
    const int kj = (tr >> 4) & 3, c15k = tr & 15;
    unsigned short* ks = K2 + ((size_t)bh * 32 + ttile) * 8192;
    const int gh = ((st * 4 + kj) * 2 + 0) * 512, gl = gh + 512;
    *(uint4*)(ks + gh + quadA * 128 + c15k * 8) = uint4{wh[0], wh[1], wh[2], wh[3]};
    *(uint4*)(ks + gh + quadB * 128 + c15k * 8) = uint4{wh[4], wh[5], wh[6], wh[7]};
    *(uint4*)(ks + gl + quadA * 128 + c15k * 8) = uint4{wl[0], wl[1], wl[2], wl[3]};
    *(uint4*)(ks + gl + quadB * 128 + c15k * 8) = uint4{wl[4], wl[5], wl[6], wl[7]};
  }
  // v transpose via LDS, then fragment-linear store
#pragma unroll
  for (int e = 0; e < 16; ++e) Vl[(seg * 16 + e) * 66 + tr] = f2bf(vv[e]);
  __syncthreads();
  {
    const int d = tid >> 2, tch = (tid & 3) * 16;
    unsigned int wv2[8];
#pragma unroll
    for (int p = 0; p < 8; ++p) {
      const unsigned short a0 = Vl[d * 66 + tch + 2*p];
      const unsigned short a1 = Vl[d * 66 + tch + 2*p + 1];
      wv2[p] = (unsigned)a0 | ((unsigned)a1 << 16);
    }
    const int dj = d >> 4, c15v = d & 15;
    const int ks2 = tch >> 5;
    const int qvA = (tch >> 3) & 3, qvB = ((tch >> 3) + 1) & 3;
    unsigned short* vs = V2 + ((size_t)bh * 32 + ttile) * 4096 + (ks2 * 4 + dj) * 512;
    *(uint4*)(vs + qvA * 128 + c15v * 8) = uint4{wv2[0], wv2[1], wv2[2], wv2[3]};
    *(uint4*)(vs + qvB * 128 + c15v * 8) = uint4{wv2[4], wv2[5], wv2[6], wv2[7]};
  }
}

// Split-K barrier-free MFMA flash attention, static-max softmax. 1 wave/block,
// 5120 blocks = (bh, qw-of-32-rows, chunk<=8 ktiles), big chunks first.
// All global loads lane-linear (fragment-linear tiles). Partial o (f32, [idx][lane]x4)
// + l (32 f32) per slot; slots ADD across chunks because max is static.
__global__ __launch_bounds__(64) void attn_part(
    const unsigned short* __restrict__ Q2, const unsigned short* __restrict__ K2,
    const unsigned short* __restrict__ V2, const float* __restrict__ tqq,
    const float* __restrict__ tkk, const float* __restrict__ curvg,
    float* __restrict__ part) {
  alignas(16) __shared__ unsigned short Pl[32 * 64];   // 4KB wave-private P tile
  const int lane = threadIdx.x;
  const int quad = lane >> 4, c15 = lane & 15;
  const int z = blockIdx.x, bh = z & 31;
  const int u = 159 - (z >> 5);          // slot-in-bh, big (qw,ch) first
  int qw, ch;
  if (u < 16)      { qw = u; ch = 0; }
  else if (u < 48) { qw = 16 + ((u - 16) >> 1); ch = (u - 16) & 1; }
  else if (u < 96) { const int s2 = u - 48; const int q3 = s2 / 3; qw = 32 + q3; ch = s2 - 3 * q3; }
  else             { const int s2 = u - 96; qw = 48 + (s2 >> 2); ch = s2 & 3; }
  const int h = bh & 15;
  const int geom = (h < 6) ? 0 : ((h < 10) ? 1 : 2);
  const int qrow0 = qw * 32;
  const f32x4 zero4 = {0.f, 0.f, 0.f, 0.f};

  // Q fragments: lane-linear loads
  const unsigned short* qbase = Q2 + ((size_t)bh * 64 + qw) * 4096;
  bf16x8 qh[2][2], ql[2][2];
#pragma unroll
  for (int qi = 0; qi < 2; ++qi)
#pragma unroll
    for (int st = 0; st < 2; ++st) {
      const int f = ((qi * 2 + st) * 2) * 512 + lane * 8;
      qh[qi][st] = *(const bf16x8*)(qbase + f);
      ql[qi][st] = *(const bf16x8*)(qbase + f + 512);
    }

  float curv = 1.f, sic = 1.f, sscale = 0.125f, Moff = 16.0f;
  f32x4 tq4[2] = {zero4, zero4};
  if (geom == 1) {
    curv = curvg[h - 6];
    sic = sqrtf(1.0f / curv);
    Moff = 4.0f;
#pragma unroll
    for (int qi = 0; qi < 2; ++qi)
      tq4[qi] = *(const f32x4*)(tqq + bh * 2048 + qrow0 + qi * 16 + quad * 4);
  } else if (geom == 2) {
    sscale = 8.0f;
    Moff = 8.0f;
  }

  const __bf16 one_b = (__bf16)1.0f;
  const bf16x8 ones = {one_b, one_b, one_b, one_b, one_b, one_b, one_b, one_b};

  f32x4 o[2][4];
  f32x4 ol[2] = {zero4, zero4};
#pragma unroll
  for (int qi = 0; qi < 2; ++qi)
#pragma unroll
    for (int dj = 0; dj < 4; ++dj) o[qi][dj] = zero4;

  const int nkt = (qw >> 1) + 1;
  const int ktB = ch * 8;
  const int ktE = (ktB + 8 < nkt) ? (ktB + 8) : nkt;
  for (int kt = ktB; kt < ktE; ++kt) {
    const int kb = kt * 64;
    const unsigned short* kbase = K2 + ((size_t)bh * 32 + kt) * 8192;
    const unsigned short* vbase = V2 + ((size_t)bh * 32 + kt) * 4096;

    // ---- S = Q.K'^T (3-product split); all loads lane-linear
    f32x4 s[2][4];
#pragma unroll
    for (int qi = 0; qi < 2; ++qi)
#pragma unroll
      for (int kj = 0; kj < 4; ++kj) s[qi][kj] = zero4;
#pragma unroll
    for (int st = 0; st < 2; ++st) {
#pragma unroll
      for (int kj = 0; kj < 4; ++kj) {
        const int f = ((st * 4 + kj) * 2) * 512 + lane * 8;
        const bf16x8 bhf = *(const bf16x8*)(kbase + f);
        const bf16x8 blf = *(const bf16x8*)(kbase + f + 512);
#pragma unroll
        for (int qi = 0; qi < 2; ++qi) {
          s[qi][kj] = __builtin_amdgcn_mfma_f32_16x16x32_bf16(qh[qi][st], bhf, s[qi][kj], 0, 0, 0);
          s[qi][kj] = __builtin_amdgcn_mfma_f32_16x16x32_bf16(ql[qi][st], bhf, s[qi][kj], 0, 0, 0);
          s[qi][kj] = __builtin_amdgcn_mfma_f32_16x16x32_bf16(qh[qi][st], blf, s[qi][kj], 0, 0, 0);
        }
      }
    }

    // ---- p = exp(score - M_static); mask only the straddling last ktile
    const bool needmask = (kt == nkt - 1);
#pragma unroll
    for (int qi = 0; qi < 2; ++qi) {
      const int qbaserow = qrow0 + qi * 16 + quad * 4;
#pragma unroll
      for (int kj = 0; kj < 4; ++kj) {
        const int skey = kj * 16 + c15;
        const int key = kb + skey;
        const f32x4 d4 = s[qi][kj];
        f32x4 p;
        if (geom == 1) {
          const float tk = tkk[bh * 2048 + key];
#pragma unroll
          for (int r = 0; r < 4; ++r) {
            const float a = fmaxf(curv * (tq4[qi][r] * tk - d4[r]), 1.0f + 1e-7f);
            const float dis = sic * __logf(a + sqrtf(a * a - 1.0f));
            p[r] = __expf(__builtin_amdgcn_rcpf(1e-6f + dis) - Moff);
          }
        } else {
#pragma unroll
          for (int r = 0; r < 4; ++r) p[r] = __expf(d4[r] * sscale - Moff);
        }
        if (needmask) {
#pragma unroll
          for (int r = 0; r < 4; ++r)
            if (key > qbaserow + r) p[r] = 0.0f;
        }
#pragma unroll
        for (int r = 0; r < 4; ++r) {
          union { float f; unsigned u2; } pv; pv.f = p[r];
          const int row = qi * 16 + quad * 4 + r;
          const int g = (skey >> 3) ^ (row & 7);
          Pl[row * 64 + g * 8 + (skey & 7)] = (unsigned short)(pv.u2 >> 16);
        }
      }
    }

    // ---- PV: O += P.V^T ; l += P.1 ; V loads lane-linear
#pragma unroll
    for (int ks2 = 0; ks2 < 2; ++ks2) {
      bf16x8 av[2];
#pragma unroll
      for (int qi = 0; qi < 2; ++qi) {
        const int m = qi * 16 + c15;
        const int g = (ks2 * 4 + quad) ^ (m & 7);
        av[qi] = *(const bf16x8*)(Pl + m * 64 + g * 8);
        ol[qi] = __builtin_amdgcn_mfma_f32_16x16x32_bf16(av[qi], ones, ol[qi], 0, 0, 0);
      }
#pragma unroll
      for (int dj = 0; dj < 4; ++dj) {
        const bf16x8 bv = *(const bf16x8*)(vbase + (ks2 * 4 + dj) * 512 + lane * 8);
#pragma unroll
        for (int qi = 0; qi < 2; ++qi)
          o[qi][dj] = __builtin_amdgcn_mfma_f32_16x16x32_bf16(av[qi], bv, o[qi][dj], 0, 0, 0);
      }
    }
  }

  // ---- partial write: slot = bh*160 + u, stride 2112 f32; o at [idx*256+lane*4], l at 2048+
  float* slot = part + (size_t)(bh * 160 + u) * 2112;
#pragma unroll
  for (int qi = 0; qi < 2; ++qi)
#pragma unroll
    for (int dj = 0; dj < 4; ++dj)
      *(f32x4*)(slot + (qi * 4 + dj) * 256 + lane * 4) = o[qi][dj];
  if (c15 == 0) {
#pragma unroll
    for (int qi = 0; qi < 2; ++qi)
      *(f32x4*)(slot + 2048 + qi * 16 + quad * 4) = ol[qi];
  }
}

// Sum chunk partials, divide, LDS-transpose, write A'y [hi|lo|hi] with 16B stores.
__global__ __launch_bounds__(64) void attn_reduce(
    const float* __restrict__ part, unsigned short* __restrict__ Ay) {
  __shared__ float Ol[32 * 65];
  const int lane = threadIdx.x;
  const int quad = lane >> 4, c15 = lane & 15;
  const int z = blockIdx.x, bh = z & 31, qw = 63 - (z >> 5);
  const int b = bh >> 4, h = bh & 15;
  const int G = qw >> 4;
  const int base = qw + 8 * G * (G - 1) + (qw & 15) * G;
  const float* slot0 = part + (size_t)(bh * 160 + base) * 2112;

  const f32x4 zero4 = {0.f, 0.f, 0.f, 0.f};
  f32x4 o[8];
  f32x4 l4[2] = {zero4, zero4};
#pragma unroll
  for (int i = 0; i < 8; ++i) o[i] = zero4;
  for (int chv = 0; chv <= G; ++chv) {
    const float* sl = slot0 + chv * 2112;
#pragma unroll
    for (int i = 0; i < 8; ++i) o[i] += *(const f32x4*)(sl + i * 256 + lane * 4);
#pragma unroll
    for (int qi = 0; qi < 2; ++qi)
      l4[qi] += *(const f32x4*)(sl + 2048 + qi * 16 + quad * 4);
  }
#pragma unroll
  for (int qi = 0; qi < 2; ++qi) {
    f32x4 invl;
#pragma unroll
    for (int r = 0; r < 4; ++r) invl[r] = __builtin_amdgcn_rcpf(l4[qi][r]);
#pragma unroll
    for (int dj = 0; dj < 4; ++dj) {
      const f32x4 val = o[qi * 4 + dj] * invl;
#pragma unroll
      for (int r = 0; r < 4; ++r)
        Ol[(qi * 16 + quad * 4 + r) * 65 + dj * 16 + c15] = val[r];
    }
  }
  __syncthreads();   // single wave, but ensure LDS visibility across lanes
  const int row = lane >> 1, half = lane & 1;
  const float* rp = Ol + row * 65 + half * 32;
  unsigned int uh[16], ul2[16];
#pragma unroll
  for (int p = 0; p < 16; ++p) {
    const float v0 = rp[2 * p], v1 = rp[2 * p + 1];
    const unsigned short h0 = f2bf(v0), h1 = f2bf(v1);
    const unsigned short g0 = f2bf(v0 - bf2f(h0)), g1 = f2bf(v1 - bf2f(h1));
    uh[p] = (unsigned)h0 | ((unsigned)h1 << 16);
    ul2[p] = (unsigned)g0 | ((unsigned)g1 << 16);
  }
  unsigned short* yp = Ay + ((size_t)(b * 2048 + qw * 32 + row)) * 3072 + h * 64 + half * 32;
#pragma unroll
  for (int c = 0; c < 4; ++c) {
    const uint4 vh = uint4{uh[4*c], uh[4*c+1], uh[4*c+2], uh[4*c+3]};
    const uint4 vl = uint4{ul2[4*c], ul2[4*c+1], ul2[4*c+2], ul2[4*c+3]};
    *(uint4*)(yp + 8 * c)        = vh;   // hi
    *(uint4*)(yp + 1024 + 8 * c) = vl;   // lo
    *(uint4*)(yp + 2048 + 8 * c) = vh;   // hi
  }
}

extern "C" void kernel_launch(void* const* d_in, const int* in_sizes, int n_in,
                              void* d_out, int out_size, void* d_ws, size_t ws_size,
                              hipStream_t stream) {
  const float* x      = (const float*)d_in[0];
  const float* qkv_w  = (const float*)d_in[1];
  const float* proj_w = (const float*)d_in[2];
  const float* proj_b = (const float*)d_in[3];
  const float* curvature = (const float*)d_in[4];
  float* out = (float*)d_out;

  char* ws = (char*)d_ws;
  unsigned short* AX   = (unsigned short*)ws;                     // phase1
  unsigned short* BW   = (unsigned short*)(ws + 25165824);
  float*          QKVF = (float*)(ws + 44040192);
  unsigned short* Q2   = (unsigned short*)ws;                     // post-prep
  unsigned short* K2   = (unsigned short*)(ws + 16777216);
  unsigned short* V2   = (unsigned short*)(ws + 33554432);
  unsigned short* BPW  = (unsigned short*)(ws + 44040192);
  float*          PART = (float*)(ws + 50331648);                 // 43,253,760 B
  unsigned short* AY   = (unsigned short*)ws;                     // post-attn
  float*          QQ   = (float*)(ws + 94371840);
  float*          KK   = (float*)(ws + 94633984);

  split3<0><<<4096, 256, 0, stream>>>(x, AX);
  split3<1><<<3072, 256, 0, stream>>>(qkv_w, BW);

  gemm_bt<0><<<dim3(24, 32), 256, 0, stream>>>(AX, BW, QKVF, nullptr, 3072, 3072);

  prep<<<1024, 256, 0, stream>>>(QKVF, Q2, K2, V2, QQ, KK, curvature);

  split3<1><<<1024, 256, 0, stream>>>(proj_w, BPW);

  attn_part<<<5120, 64, 0, stream>>>(Q2, K2, V2, QQ, KK, curvature, PART);

  attn_reduce<<<2048, 64, 0, stream>>>(PART, AY);

  gemm_bt<1><<<dim3(8, 32), 256, 0, stream>>>(AY, BPW, out, proj_b, 1024, 3072);
}